// Round 11
// baseline (43.736 us; speedup 1.0000x reference)
//
#include <hip/hip_runtime.h>

#define T_DIM 4096
#define QPR 32            // float4 quads per (b,t) row (D=128)
#define CH 8              // chunk length along t
#define CPS (T_DIM / CH)  // 512 chunks per series

typedef float floatx4 __attribute__((ext_vector_type(4)));

// One thread owns CH=8 consecutive t's of one (b, 4-d) column.
// Forward register scan -> (a,kb) stored IN PLACE over Rv; backward scan
// carries (b, kf-1); select-free epilogue:
//   fill = a + trel*(b-a)*rcp(max3(trel+kfm1, trel, 1))
// Round-11 lever: one asm pin with all 16 load destinations as "+v"
// operands -> all 64 payload VGPRs provably live at once -> the compiler
// MUST issue all 16 loads before a single vmcnt wait (one latency
// round-trip; at VGPR=44 it was serializing into 2-3 dependent batches).
__global__ void __launch_bounds__(256, 4) imputer_kernel(
    const float* __restrict__ x, float* __restrict__ out) {
    // XCD-aware swizzle: gridDim.x = 4096 = 8 XCDs * 512.
    int bid = blockIdx.x;
    int wg  = (bid & 7) * 512 + (bid >> 3);
    int n   = wg * 256 + threadIdx.x;

    int q  = n & (QPR - 1);
    int ch = n >> 5;                  // global chunk id
    int t0 = (ch & (CPS - 1)) << 3;
    int bb = ch >> 9;
    int sb = bb * (T_DIM * QPR) + q;  // quad index of (bb, t=0, q)
    int base = sb + t0 * QPR;

    const floatx4* __restrict__ x4 = reinterpret_cast<const floatx4*>(x);

    // ---- 16-load burst: 8 chunk rows + 4+4 clamped halo rows ----
    floatx4 R[CH];
#pragma unroll
    for (int k = 0; k < CH; ++k) R[k] = x4[base + k * QPR];
    floatx4 PM[4], PS[4];
#pragma unroll
    for (int j = 0; j < 4; ++j) {
        PM[j] = x4[sb + max(t0 - 1 - j, 0) * QPR];
        PS[j] = x4[sb + min(t0 + CH + j, T_DIM - 1) * QPR];
    }
    // Pin: all 16 vectors live simultaneously -> single vmcnt round-trip.
    asm volatile("" : "+v"(R[0]), "+v"(R[1]), "+v"(R[2]), "+v"(R[3]),
                      "+v"(R[4]), "+v"(R[5]), "+v"(R[6]), "+v"(R[7]),
                      "+v"(PM[0]), "+v"(PM[1]), "+v"(PM[2]), "+v"(PM[3]),
                      "+v"(PS[0]), "+v"(PS[1]), "+v"(PS[2]), "+v"(PS[3]));

    float Rv[CH][4];
#pragma unroll
    for (int k = 0; k < CH; ++k) {
#pragma unroll
        for (int c = 0; c < 4; ++c) Rv[k][c] = R[k][c];
    }
    float PMv[4][4], PSv[4][4];
#pragma unroll
    for (int j = 0; j < 4; ++j) {
#pragma unroll
        for (int c = 0; c < 4; ++c) { PMv[j][c] = PM[j][c]; PSv[j][c] = PS[j][c]; }
    }

    // ---- prefix seed (A, KB) at position t0-1: far-to-near, no guard ----
    float kbmax = (float)max(t0 - 1, 0);
    float A[4], KB[4];
#pragma unroll
    for (int c = 0; c < 4; ++c) { A[c] = 0.f; KB[c] = (float)t0; }  // s=-1 default
#pragma unroll
    for (int j = 3; j >= 0; --j) {
        float kbj = fminf((float)j, kbmax);
#pragma unroll
        for (int c = 0; c < 4; ++c)
            if (PMv[j][c] != 0.f) { A[c] = PMv[j][c]; KB[c] = kbj; }
    }

    // ---- suffix seed (Bt, KFm1=kf-1) at position t0+CH-1 ----
    float kfmax = (float)(T_DIM - CH - t0);
    float Bt[4], KFm1[4];
#pragma unroll
    for (int c = 0; c < 4; ++c) { Bt[c] = 0.f; KFm1[c] = kfmax - 1.f; }  // nv=T default
#pragma unroll
    for (int j = 3; j >= 0; --j) {
        float kfj = fminf((float)(j + 1), kfmax);
#pragma unroll
        for (int c = 0; c < 4; ++c)
            if (PSv[j][c] != 0.f) { Bt[c] = PSv[j][c]; KFm1[c] = kfj - 1.f; }
    }

    // ---- deep halo (rare): gap extends past the 4 shallow rows ----
    bool nb = false, nf = false;
#pragma unroll
    for (int c = 0; c < 4; ++c) {
        nb = nb || (A[c] == 0.f && Rv[0][c] == 0.f);
        nf = nf || (Bt[c] == 0.f && Rv[CH - 1][c] == 0.f);
    }
    if (__any(nb && t0 > 4)) {
        if (nb && t0 > 4) {
#pragma unroll
            for (int c = 0; c < 4; ++c) {
                if (A[c] == 0.f && Rv[0][c] == 0.f) {
                    int s = t0 - 5;
                    while (s >= 0 && x[(sb + s * QPR) * 4 + c] == 0.f) --s;
                    if (s >= 0) { A[c] = x[(sb + s * QPR) * 4 + c]; KB[c] = (float)(t0 - 1 - s); }
                    // else: default (A=0, KB=t0) is the correct s=-1 state
                }
            }
        }
    }
    if (__any(nf && (t0 + 12) < T_DIM)) {
        if (nf && (t0 + 12) < T_DIM) {
#pragma unroll
            for (int c = 0; c < 4; ++c) {
                if (Bt[c] == 0.f && Rv[CH - 1][c] == 0.f) {
                    int e = t0 + CH + 4;
                    while (e < T_DIM && x[(sb + e * QPR) * 4 + c] == 0.f) ++e;
                    if (e < T_DIM) { Bt[c] = x[(sb + e * QPR) * 4 + c]; KFm1[c] = (float)(e - (t0 + CH - 1)) - 1.f; }
                    else           { KFm1[c] = kfmax - 1.f; }  // whole tail invalid
                }
            }
        }
    }

    // ---- forward sweep: (a, kb) per position, a stored in place over Rv ----
    float kb[CH][4];
#pragma unroll
    for (int k = 0; k < CH; ++k) {
#pragma unroll
        for (int c = 0; c < 4; ++c) {
            bool valid = (Rv[k][c] != 0.f);
            A[c]  = valid ? Rv[k][c] : A[c];
            KB[c] = valid ? 0.f : (KB[c] + 1.f);
            Rv[k][c] = A[c];
            kb[k][c] = KB[c];
        }
    }

    // ---- backward sweep + select-free epilogue + NT store ----
    float tf = (float)t0;
    floatx4* __restrict__ out4 = reinterpret_cast<floatx4*>(out);
#pragma unroll
    for (int k = CH - 1; k >= 0; --k) {
        floatx4 o;
#pragma unroll
        for (int c = 0; c < 4; ++c) {
            float trel = fminf(kb[k][c], tf + (float)k);          // min(kb, t)
            float u    = trel + KFm1[c];                          // denom
            float den  = fmaxf(fmaxf(u, trel), 1.f);              // v_max3
            o[c] = Rv[k][c] + trel * (Bt[c] - Rv[k][c]) * __builtin_amdgcn_rcpf(den);
            bool valid = (kb[k][c] == 0.f);
            Bt[c]   = valid ? Rv[k][c] : Bt[c];
            KFm1[c] = valid ? 0.f : (KFm1[c] + 1.f);
        }
        __builtin_nontemporal_store(o, &out4[base + k * QPR]);
    }
}

extern "C" void kernel_launch(void* const* d_in, const int* in_sizes, int n_in,
                              void* d_out, int out_size, void* d_ws, size_t ws_size,
                              hipStream_t stream) {
    const float* x = (const float*)d_in[0];
    float* out = (float*)d_out;
    int threads = 256;
    int blocks = (in_sizes[0] / 4 / CH) / threads;   // 4096, exact (8 | 4096)
    imputer_kernel<<<blocks, threads, 0, stream>>>(x, out);
}

// Round 12
// 42.807 us; speedup vs baseline: 1.0217x; 1.0217x over previous
//
#include <hip/hip_runtime.h>

#define T_DIM 4096
#define QPR 32            // float4 quads per (b,t) row (D=128)
#define CH 8              // chunk length along t
#define CPS (T_DIM / CH)  // 512 chunks per series

typedef float floatx4 __attribute__((ext_vector_type(4)));  // native vec for NT store

// FINAL (round-10 best, 42.8 us = ~97% of the 6.29 TB/s mixed-stream copy
// ceiling at 265 MB user traffic).
// One thread owns CH=8 consecutive t's of one (b, 4-d) column.
// Forward register scan -> (a, kb); backward register scan -> (b, kf);
// select-free epilogue: fill = a + trel*(b-a)*rcp(max3(trel+kf-1, trel, 1)).
//  - NT stores: write-once output skips L2 allocate.
//  - XCD swizzle: contiguous t-range per XCD -> halo rows are same-XCD L2 hits.
__global__ void __launch_bounds__(256, 4) imputer_kernel(
    const float* __restrict__ x, float* __restrict__ out) {
    // XCD-aware swizzle: gridDim.x = 4096 = 8 XCDs * 512.
    int bid = blockIdx.x;
    int wg  = (bid & 7) * 512 + (bid >> 3);
    int n   = wg * 256 + threadIdx.x;

    int q  = n & (QPR - 1);
    int ch = n >> 5;                  // global chunk id
    int t0 = (ch & (CPS - 1)) << 3;
    int bb = ch >> 9;
    int sb = bb * (T_DIM * QPR) + q;  // quad index of (bb, t=0, q)
    int base = sb + t0 * QPR;

    const float4* __restrict__ x4 = reinterpret_cast<const float4*>(x);

    // ---- 8 chunk rows + 4+4 clamped halo rows ----
    float4 R[CH];
    float4 PM[4], PS[4];
#pragma unroll
    for (int k = 0; k < CH; ++k) R[k] = x4[base + k * QPR];
#pragma unroll
    for (int j = 0; j < 4; ++j) {
        PM[j] = x4[sb + max(t0 - 1 - j, 0) * QPR];
        PS[j] = x4[sb + min(t0 + CH + j, T_DIM - 1) * QPR];
    }
    __builtin_amdgcn_sched_barrier(0);

    float Rv[CH][4];
#pragma unroll
    for (int k = 0; k < CH; ++k) {
        Rv[k][0] = R[k].x; Rv[k][1] = R[k].y; Rv[k][2] = R[k].z; Rv[k][3] = R[k].w;
    }
    float PMv[4][4], PSv[4][4];
#pragma unroll
    for (int j = 0; j < 4; ++j) {
        PMv[j][0] = PM[j].x; PMv[j][1] = PM[j].y; PMv[j][2] = PM[j].z; PMv[j][3] = PM[j].w;
        PSv[j][0] = PS[j].x; PSv[j][1] = PS[j].y; PSv[j][2] = PS[j].z; PSv[j][3] = PS[j].w;
    }

    // ---- prefix merge: state (A, KB) at position t0-1 ----
    float kbmax = (float)max(t0 - 1, 0);
    float A[4], KB[4];
#pragma unroll
    for (int c = 0; c < 4; ++c) { A[c] = 0.f; KB[c] = (float)t0; }  // s=-1 default
#pragma unroll
    for (int j = 0; j < 4; ++j) {
        float kbj = fminf((float)j, kbmax);
#pragma unroll
        for (int c = 0; c < 4; ++c)
            if (A[c] == 0.f && PMv[j][c] != 0.f) { A[c] = PMv[j][c]; KB[c] = kbj; }
    }

    // ---- suffix merge: state (Bt, KF) at position t_end = t0+CH-1 ----
    float kfmax = (float)(T_DIM - CH - t0);   // = (T-1) - t_end
    float Bt[4], KF[4];
#pragma unroll
    for (int c = 0; c < 4; ++c) { Bt[c] = 0.f; KF[c] = kfmax; }  // nv=T default
#pragma unroll
    for (int j = 0; j < 4; ++j) {
        float kfj = fminf((float)(j + 1), kfmax);
#pragma unroll
        for (int c = 0; c < 4; ++c)
            if (Bt[c] == 0.f && PSv[j][c] != 0.f) { Bt[c] = PSv[j][c]; KF[c] = kfj; }
    }

    // ---- deep halo (rare): gap extends past the 4 shallow rows ----
    bool nb = false, nf = false;
#pragma unroll
    for (int c = 0; c < 4; ++c) {
        nb = nb || (A[c] == 0.f && Rv[0][c] == 0.f);
        nf = nf || (Bt[c] == 0.f && Rv[CH - 1][c] == 0.f);
    }
    if (__any(nb && t0 > 4)) {
        if (nb && t0 > 4) {
#pragma unroll
            for (int c = 0; c < 4; ++c) {
                if (A[c] == 0.f && Rv[0][c] == 0.f) {
                    int s = t0 - 5;
                    while (s >= 0 && x[(sb + s * QPR) * 4 + c] == 0.f) --s;
                    if (s >= 0) { A[c] = x[(sb + s * QPR) * 4 + c]; KB[c] = (float)(t0 - 1 - s); }
                    // else: default (A=0, KB=t0) is the correct s=-1 state
                }
            }
        }
    }
    if (__any(nf && (t0 + 12) < T_DIM)) {
        if (nf && (t0 + 12) < T_DIM) {
#pragma unroll
            for (int c = 0; c < 4; ++c) {
                if (Bt[c] == 0.f && Rv[CH - 1][c] == 0.f) {
                    int e = t0 + CH + 4;
                    while (e < T_DIM && x[(sb + e * QPR) * 4 + c] == 0.f) ++e;
                    if (e < T_DIM) { Bt[c] = x[(sb + e * QPR) * 4 + c]; KF[c] = (float)(e - (t0 + CH - 1)); }
                    else           { KF[c] = kfmax; }  // whole tail invalid: b=0, end=T-1
                }
            }
        }
    }

    // ---- forward sweep: per-position (a, kb) ----
    float av[CH][4], kb[CH][4];
#pragma unroll
    for (int k = 0; k < CH; ++k) {
#pragma unroll
        for (int c = 0; c < 4; ++c) {
            bool valid = (Rv[k][c] != 0.f);
            A[c]  = valid ? Rv[k][c] : A[c];
            KB[c] = valid ? 0.f : (KB[c] + 1.f);
            av[k][c] = A[c];
            kb[k][c] = KB[c];
        }
    }

    // ---- backward sweep + select-free epilogue + NT store ----
    float tf = (float)t0;
    floatx4* __restrict__ out4 = reinterpret_cast<floatx4*>(out);
#pragma unroll
    for (int k = CH - 1; k >= 0; --k) {
        float o[4];
#pragma unroll
        for (int c = 0; c < 4; ++c) {
            float trel = fminf(kb[k][c], tf + (float)k);          // min(kb, t)
            float u    = trel + KF[c] - 1.f;                      // denom
            float den  = fmaxf(fmaxf(u, trel), 1.f);              // v_max3
            o[c] = av[k][c] + trel * (Bt[c] - av[k][c]) * __builtin_amdgcn_rcpf(den);
            bool valid = (kb[k][c] == 0.f);
            Bt[c] = valid ? av[k][c] : Bt[c];
            KF[c] = valid ? 1.f : (KF[c] + 1.f);
        }
        floatx4 ov = {o[0], o[1], o[2], o[3]};
        __builtin_nontemporal_store(ov, &out4[base + k * QPR]);
    }
}

extern "C" void kernel_launch(void* const* d_in, const int* in_sizes, int n_in,
                              void* d_out, int out_size, void* d_ws, size_t ws_size,
                              hipStream_t stream) {
    const float* x = (const float*)d_in[0];
    float* out = (float*)d_out;
    int threads = 256;
    int blocks = (in_sizes[0] / 4 / CH) / threads;   // 4096, exact (8 | 4096)
    imputer_kernel<<<blocks, threads, 0, stream>>>(x, out);
}